// Round 3
// baseline (151.952 us; speedup 1.0000x reference)
//
#include <hip/hip_runtime.h>

// MTH spiking-threshold recurrence: elementwise over N = B*C*H*W positions,
// T=4 timesteps, K=8 thresholds. Memory-bound streaming kernel.
//
// x layout (flat): [T+1, N]; plane 0 is the bias. out: [T+1, N]; plane 0 = 0.
//
// Exactness notes (absmax must be ~0):
//  - pos_k/neg_k are monotone in k, so the reference's diff-and-sum collapses
//    to "thre of the first satisfied k" -> descending select chain (bit-exact).
//  - spike = sp - sn with at most one of sp/sn nonzero -> exact.
//  - /denom for denom=1,2,4 is an exact power-of-2 multiply; denom=3 keeps
//    true IEEE division (2 divides per element, timestep t==2 only).
//  - mem update keeps the reference's left-to-right association:
//    (((mem + xt) - bias) + ein) - eout.

constexpr int T_STEPS = 4;
constexpr int K_THR   = 8;

// clang-native vector type: __builtin_nontemporal_store requires a vector of
// scalars, not HIP's float4 class.
typedef float f32x4 __attribute__((ext_vector_type(4)));

__global__ __launch_bounds__(256) void mth_kernel(
    const float* __restrict__ x, const float* __restrict__ thresh,
    float* __restrict__ out, int n4)
{
    // thresh is uniform: force it into an SGPR so threshold tables scalarize.
    const float th = __uint_as_float(
        __builtin_amdgcn_readfirstlane(__float_as_uint(thresh[0])));

    const int i = blockIdx.x * blockDim.x + threadIdx.x;
    if (i >= n4) return;

    const f32x4* __restrict__ xv = reinterpret_cast<const f32x4*>(x);
    f32x4* __restrict__ ov       = reinterpret_cast<f32x4*>(out);

    // Threshold tables (loop-invariant): thre[k] = th * 2^-k (exact),
    // tt[k] = 0.75f * thre[k] (same single rounding as the reference).
    float thre[K_THR], tt[K_THR];
    #pragma unroll
    for (int k = 0; k < K_THR; ++k) {
        thre[k] = th * (1.0f / (float)(1 << k));
        tt[k]   = 0.75f * thre[k];
    }

    // Hoist ALL global loads: 5 independent dwordx4 in flight per thread.
    const f32x4 b4 = xv[i];
    f32x4 xt4[T_STEPS];
    #pragma unroll
    for (int t = 0; t < T_STEPS; ++t)
        xt4[t] = xv[(size_t)(t + 1) * n4 + i];

    // Plane 0 of the output is zeros (harness poisons d_out).
    __builtin_nontemporal_store((f32x4){0.f, 0.f, 0.f, 0.f}, &ov[i]);

    float b[4]    = {b4.x, b4.y, b4.z, b4.w};
    float mem[4]  = {0.f, 0.f, 0.f, 0.f};
    float cum[4]  = {0.f, 0.f, 0.f, 0.f};
    float ein[4]  = {b4.x, b4.y, b4.z, b4.w};
    float eout[4] = {0.f, 0.f, 0.f, 0.f};

    #pragma unroll
    for (int t = 0; t < T_STEPS; ++t) {
        const float xt[4] = {xt4[t].x, xt4[t].y, xt4[t].z, xt4[t].w};
        f32x4 sp4;

        #pragma unroll
        for (int j = 0; j < 4; ++j) {
            // Reference op order: ((((mem + xt) - bias) + ein) - eout)
            float m = (((mem[j] + xt[j]) - b[j]) + ein[j]) - eout[j];
            float c = cum[j] + eout[j];

            // Descending select chains: last writer = smallest satisfying k
            // (monotone conditions) == the reference's first-difference pick.
            float sp = 0.f, sn = 0.f;
            #pragma unroll
            for (int k = K_THR - 1; k >= 0; --k) {
                sp = (m >= tt[k]) ? thre[k] : sp;                    // cmp+cndmask
                sn = (m <= -tt[k] && c >= thre[k]) ? thre[k] : sn;   // 2 cmp+cndmask
            }
            const float spike = sp - sn;   // at most one nonzero -> exact

            m -= spike;
            c += spike;
            const float d = xt[j] - b[j];
            if (t == 0)      { ein[j] += d;         eout[j] += spike;         }
            else if (t == 1) { ein[j] += d * 0.5f;  eout[j] += spike * 0.5f;  }
            else if (t == 2) { ein[j] += d / 3.0f;  eout[j] += spike / 3.0f;  } // IEEE div
            else             { ein[j] += d * 0.25f; eout[j] += spike * 0.25f; }

            mem[j] = m; cum[j] = c; sp4[j] = spike;
        }

        __builtin_nontemporal_store(sp4, &ov[(size_t)(t + 1) * n4 + i]);
    }
}

extern "C" void kernel_launch(void* const* d_in, const int* in_sizes, int n_in,
                              void* d_out, int out_size, void* d_ws, size_t ws_size,
                              hipStream_t stream)
{
    const float* x      = (const float*)d_in[0];
    const float* thresh = (const float*)d_in[1];
    float* out          = (float*)d_out;

    const int N  = in_sizes[0] / (T_STEPS + 1);
    const int n4 = N / 4;

    const int block = 256;
    const int grid  = (n4 + block - 1) / block;   // 4096 blocks
    mth_kernel<<<grid, block, 0, stream>>>(x, thresh, out, n4);
}